// Round 1
// baseline (676.491 us; speedup 1.0000x reference)
//
#include <hip/hip_runtime.h>
#include <math.h>

#define NEG_INF (-__builtin_inff())

// Top-2 semantics identical to jax.lax.top_k(x, 2).
// Branchless update; NEG_INF input is a no-op (safe padding for inactive lanes).
__device__ __forceinline__ void top2_update(float v, float& m1, float& m2) {
    float nm1 = fmaxf(m1, v);
    m2 = fmaxf(m2, fminf(m1, v));
    m1 = nm1;
}

__device__ __forceinline__ void upd4(float4 v, float& m1, float& m2) {
    top2_update(v.x, m1, m2); top2_update(v.y, m1, m2);
    top2_update(v.z, m1, m2); top2_update(v.w, m1, m2);
}

// Merge two (top1, top2) pairs (each with m1 >= m2) into one.
__device__ __forceinline__ void top2_merge(float o1, float o2, float& m1, float& m2) {
    float hi = fmaxf(m1, o1);
    float lo = fminf(m1, o1);
    m2 = fmaxf(lo, fmaxf(m2, o2));
    m1 = hi;
}

// Monotonic unsigned encoding of float (order-preserving); enc(x) > 0 for all
// finite x, so a zeroed accumulator is a safe identity for atomicMax.
__device__ __forceinline__ unsigned int enc_float(float f) {
    unsigned int b = __float_as_uint(f);
    return (b & 0x80000000u) ? ~b : (b | 0x80000000u);
}

// Branchless element select from a float4 (e in [0,3]).
__device__ __forceinline__ float sel4(float4 v, int e) {
    float xy = (e & 1) ? v.y : v.x;
    float zw = (e & 1) ? v.w : v.z;
    return (e & 2) ? zw : xy;
}

// Branchless select across the 4 row-groups (g in [0,3]) then the element.
// g/e are wave-uniform (derived from the scalar target), so these fold to
// scalar-condition cndmasks.
__device__ __forceinline__ float selg(float4 a0, float4 a1, float4 a2, float4 a3,
                                      int g, int e) {
    float s0 = sel4(a0, e), s1 = sel4(a1, e), s2 = sel4(a2, e), s3 = sel4(a3, e);
    float lo = (g & 1) ? s1 : s0;
    float hi = (g & 1) ? s3 : s2;
    return (g & 2) ? hi : lo;
}

// Specialized for C == 1000: 250 float4 per row = 3 full wave-groups + 58-lane tail.
//
// Pipelined variant: row k+1's 12 loads (12 KB/wave) are issued as soon as row
// k's payload has been folded into the 6 top-2 accumulators, so the butterfly
// reduction + epilogue (~1000 cy) always runs with a full row in flight.
// __launch_bounds__(256, 4) licenses up to 128 VGPRs so the 48-reg payload can
// actually stay resident (previous build reported VGPR=44 < payload => the
// compiler had serialized the loads, capping MLP and delivered BW at ~3.85 TB/s).
//
// targets[row] is wave-uniform -> scalar load issued with the row; the target
// logit is extracted from the already-loaded registers (no dependent re-load
// chain), and the lane owning the target column performs the softmax + store.
__global__ __launch_bounds__(256, 4) void margin_softmax_kernel(
    const float* __restrict__ out1,
    const float* __restrict__ out2,
    const float* __restrict__ mim,
    const int*   __restrict__ targets,
    float*       __restrict__ d_out,   // [0]=uint-encoded running max, [1 + 3*row + j] = softmax
    int N)
{
    const int lane          = threadIdx.x & 63;
    const int wave_in_blk   = threadIdx.x >> 6;
    const int waves_per_blk = blockDim.x >> 6;
    const int gwave  = blockIdx.x * waves_per_blk + wave_in_blk;
    const int nwaves = gridDim.x * waves_per_blk;

    const float4 pad = make_float4(NEG_INF, NEG_INF, NEG_INF, NEG_INF);

    float lane_run = NEG_INF;  // running max over outputs1 & outputs2

    float4 A0, A1, A2, A3, B0, B1, B2, B3, M0, M1, M2, M3;
    int tgt = 0;

    // Wave-uniform row => SGPR base + single lane*16 voffset; group offsets are
    // immediate offsets, so issuing all 12 loads costs no extra address VGPRs.
#define ISSUE_ROW(r)                                                        \
    do {                                                                    \
        const size_t base_ = (size_t)(r) * 1000u;                           \
        const float4* q1 = (const float4*)(out1 + base_);                   \
        const float4* q2 = (const float4*)(out2 + base_);                   \
        const float4* q3 = (const float4*)(mim  + base_);                   \
        tgt = targets[r];                                                   \
        A0 = q1[lane];       B0 = q2[lane];       M0 = q3[lane];            \
        A1 = q1[lane + 64];  B1 = q2[lane + 64];  M1 = q3[lane + 64];       \
        A2 = q1[lane + 128]; B2 = q2[lane + 128]; M2 = q3[lane + 128];      \
        A3 = pad; B3 = pad; M3 = pad;                                       \
        if (lane < 58) {        /* 250 - 192 = 58 tail float4s */           \
            A3 = q1[lane + 192]; B3 = q2[lane + 192]; M3 = q3[lane + 192];  \
        }                                                                   \
    } while (0)

    int row = gwave;
    if (row < N) ISSUE_ROW(row);   // pipeline prologue

    for (; row < N; row += nwaves) {
        const int nrow = row + nwaves;

        float a1 = NEG_INF, a2 = NEG_INF;   // outputs1 top-2
        float b1 = NEG_INF, b2 = NEG_INF;   // outputs2 top-2
        float c1 = NEG_INF, c2 = NEG_INF;   // mimic    top-2

        // Consume in issue order so registers free as data arrives.
        upd4(A0, a1, a2); upd4(B0, b1, b2); upd4(M0, c1, c2);
        upd4(A1, a1, a2); upd4(B1, b1, b2); upd4(M1, c1, c2);
        upd4(A2, a1, a2); upd4(B2, b1, b2); upd4(M2, c1, c2);
        upd4(A3, a1, a2); upd4(B3, b1, b2); upd4(M3, c1, c2);

        // Extract the target logit from the payload registers (all wave-uniform
        // selects) BEFORE the payload/tgt are overwritten by the prefetch.
        const int q  = tgt >> 2;     // float4 chunk index of target column
        const int lt = q & 63;       // lane that owns it
        const int g  = q >> 6;       // which group register
        const int e  = tgt & 3;      // element within the float4
        float tv1 = selg(A0, A1, A2, A3, g, e);
        float tv2 = selg(B0, B1, B2, B3, g, e);
        float tv3 = selg(M0, M1, M2, M3, g, e);

        // Prefetch next row: 12 KB in flight across the whole reduction below.
        if (nrow < N) ISSUE_ROW(nrow);

        // 64-lane butterfly reduce of the three (top1, top2) pairs.
        // Pure register/DS ops -> no vmcnt waits on the in-flight prefetch.
        #pragma unroll
        for (int off = 32; off >= 1; off >>= 1) {
            float o1, o2;
            o1 = __shfl_xor(a1, off); o2 = __shfl_xor(a2, off); top2_merge(o1, o2, a1, a2);
            o1 = __shfl_xor(b1, off); o2 = __shfl_xor(b2, off); top2_merge(o1, o2, b1, b2);
            o1 = __shfl_xor(c1, off); o2 = __shfl_xor(c2, off); top2_merge(o1, o2, c1, c2);
        }

        // Post-butterfly, a1/b1 are wave-uniform.
        lane_run = fmaxf(lane_run, fmaxf(a1, b1));

        // The lane holding the target logit does the epilogue: pure ALU + 12B store.
        if (lane == lt) {
            // margin = (tgt_logit == top1) ? top1 - top2 : 0  (exact fp equality, same values as ref)
            float d1 = (tv1 == a1) ? (a1 - a2) : 0.0f;
            float d2 = (tv2 == b1) ? (b1 - b2) : 0.0f;
            float d3 = (tv3 == c1) ? (c1 - c2) : 0.0f;
            // softmax over (d1,d2,d3) / T, T = 2.0
            float x1 = d1 * 0.5f, x2 = d2 * 0.5f, x3 = d3 * 0.5f;
            float mx = fmaxf(x1, fmaxf(x2, x3));
            float e1 = expf(x1 - mx), e2 = expf(x2 - mx), e3 = expf(x3 - mx);
            float inv = 1.0f / (e1 + e2 + e3);
            float* o = d_out + 1 + (size_t)row * 3;
            o[0] = e1 * inv;
            o[1] = e2 * inv;
            o[2] = e3 * inv;
        }
    }
#undef ISSUE_ROW

    // lane_run is wave-uniform; reduce across the block, one atomic per block.
    __shared__ float smax[8];
    if (lane == 0) smax[wave_in_blk] = lane_run;
    __syncthreads();
    if (threadIdx.x == 0) {
        float m = smax[0];
        for (int i = 1; i < waves_per_blk; i++) m = fmaxf(m, smax[i]);
        atomicMax((unsigned int*)d_out, enc_float(m));
    }
}

__global__ void finalize_max_kernel(float* d_out) {
    unsigned int u = ((unsigned int*)d_out)[0];
    unsigned int b = (u & 0x80000000u) ? (u ^ 0x80000000u) : ~u;
    d_out[0] = __uint_as_float(b);
}

extern "C" void kernel_launch(void* const* d_in, const int* in_sizes, int n_in,
                              void* d_out, int out_size, void* d_ws, size_t ws_size,
                              hipStream_t stream) {
    const float* out1    = (const float*)d_in[0];
    const float* out2    = (const float*)d_in[1];
    const float* mim     = (const float*)d_in[2];
    const int*   targets = (const int*)  d_in[3];

    const int N = in_sizes[3];            // 65536 (C fixed at 1000 in the kernel)

    // d_out[0] doubles as the uint atomicMax accumulator; enc(x) > 0 for all
    // finite x, so zero is the identity. Decoded in-place by the epilogue.
    (void)hipMemsetAsync(d_out, 0, sizeof(unsigned int), stream);

    // 2048 blocks x 256 threads = 8192 waves; 8 rows per wave (grid-stride).
    margin_softmax_kernel<<<2048, 256, 0, stream>>>(
        out1, out2, mim, targets, (float*)d_out, N);

    finalize_max_kernel<<<1, 1, 0, stream>>>((float*)d_out);
}